// Round 12
// baseline (199.413 us; speedup 1.0000x reference)
//
#include <hip/hip_runtime.h>

typedef unsigned short ushort_t;
typedef __bf16 bf16x8 __attribute__((ext_vector_type(8)));
typedef float f32x4 __attribute__((ext_vector_type(4)));

// ---- problem constants ----
#define NPTS   49152     // B*R*SR
#define KNBR   8
#define PTS_A  16        // points per block, kernel A -> 128 neighbor rows
#define NBLK_A (NPTS / PTS_A)    // 3072
#define PTS_B  32        // points per block, kernel B
#define NBLK_B (NPTS / PTS_B)    // 1536

// ---- workspace layout (ushort elements) ----
// big weights: Wswz[(k/8)*256*8 + n*8 + (k%8)], K zero-padded
// final weights (N=16 pad): Wf[(k/8)*16*8 + n*8 + (k%8)], K=256
#define W1S_OFF   0         // K=44 ->64
#define W2S_OFF   16384     // K=256
#define WA1S_OFF  81920     // K=256
#define WC1S_OFF  147456    // K=280 ->288
#define WA2S_OFF  221184    // 4096 (wa2 in col 0)
#define WC2S_OFF  225280    // 4096 (wc2 in cols 0..2)
#define WS_WEIGHT 229376
#define AGG_OFF   229376    // agg[49152][256] bf16 = 12.58M ushorts (25.2 MB)

__device__ __forceinline__ float b2f(ushort_t u) {
    return __builtin_bit_cast(float, ((unsigned)u) << 16);
}
// RNE f2b (prep only, cold path)
__device__ __forceinline__ ushort_t f2b(float f) {
    unsigned x = __builtin_bit_cast(unsigned, f);
    unsigned r = x + 0x7fffu + ((x >> 16) & 1u);
    return (ushort_t)(r >> 16);
}
// cheap round-half-up f2b (2 VALU ops, hot path)
__device__ __forceinline__ ushort_t f2bc(float f) {
    unsigned x = __builtin_bit_cast(unsigned, f);
    return (ushort_t)((x + 0x8000u) >> 16);
}

// ------------------------------------------------------------------
// prep: swizzle fp32 weights into bf16 MFMA-B fragment order.
// (round-0 verbatim)
// ------------------------------------------------------------------
__global__ __launch_bounds__(256) void prep_swizzle(
    const float* __restrict__ w1, const float* __restrict__ w2,
    const float* __restrict__ wa1, const float* __restrict__ wc1,
    const float* __restrict__ wa2, const float* __restrict__ wc2,
    ushort_t* __restrict__ ws)
{
    int idx = blockIdx.x * 256 + threadIdx.x;
    if (idx >= WS_WEIGHT) return;

    if (idx >= WA2S_OFF) {   // final-projection matrices, N=16 pad
        int off2 = idx - WA2S_OFF;
        int mat = off2 >> 12;          // 0: wa2, 1: wc2
        int off = off2 & 4095;
        int kb = off >> 7, rem = off & 127;
        int n = rem >> 3, j = rem & 7;
        int k = kb * 8 + j;
        float v = 0.f;
        if (mat == 0) { if (n == 0) v = wa2[k]; }
        else          { if (n < 3)  v = wc2[k * 3 + n]; }
        ws[idx] = f2b(v);
        return;
    }

    const float* src; int off, srcK, base;
    if (idx < W2S_OFF)        { src = w1;  base = W1S_OFF;  off = idx - W1S_OFF;  srcK = 44;  }
    else if (idx < WA1S_OFF)  { src = w2;  base = W2S_OFF;  off = idx - W2S_OFF;  srcK = 256; }
    else if (idx < WC1S_OFF)  { src = wa1; base = WA1S_OFF; off = idx - WA1S_OFF; srcK = 256; }
    else                      { src = wc1; base = WC1S_OFF; off = idx - WC1S_OFF; srcK = 280; }
    int kb  = off >> 11;          // /(256*8)
    int rem = off & 2047;
    int j = rem >> 8;             // k%8
    int n = rem & 255;
    int k = kb * 8 + j;
    float v = (k < srcK) ? src[k * 256 + n] : 0.f;
    ws[base + kb * 2048 + n * 8 + j] = f2b(v);
}

// ------------------------------------------------------------------
// kernel A: per-neighbor MLP (44->256->256) + weighted aggregation.
// Round-11 structure (best measured: pa_mlp ~76us) + two extensions of
// the proven pipe-diverse barrier-overlap mechanism:
//  (1) bias+relu of layer-1 applied IN REGISTERS before B2 (no LDS
//      dependency) -> overlaps other waves' L1 MFMA tails; post-B2
//      epilogue-1 is pure cvt+ds_write.
//  (2) sWn via 8-lane shfl tree inside staging (pre-B1); removes the
//      serial post-B1 tid<128 section (no sWraw round-trip).
//  (3) b2 loads hoisted above B3.
// Own-k-tile early layer-2 start (r11) retained: after epi-1, wave
// (wm,wn) runs k-tiles ki=2wn,2wn+1 on its own rows pre-barrier.
// ------------------------------------------------------------------
__global__ __launch_bounds__(512, 4) void pa_mlp(
    const float* __restrict__ emb, const float* __restrict__ dists,
    const int* __restrict__ mask,  const float* __restrict__ b1,
    const float* __restrict__ b2,  const ushort_t* __restrict__ ws,
    ushort_t* __restrict__ aggg)
{
    __shared__ __align__(16) ushort_t uH1[128 * 264];  // phase1: sFeat[128][72]; phase2: sH1[128][264]
    __shared__ __align__(16) float sWn[128];
    ushort_t (*sFeat)[72] = (ushort_t(*)[72])uH1;
    ushort_t (*sH1)[264]  = (ushort_t(*)[264])uH1;

    const int tid  = threadIdx.x;
    const int lane = tid & 63;
    const int wv   = tid >> 6;          // 0..7
    const int wm   = wv >> 2;           // 0..1  (M half: rows 0..63 / 64..127)
    const int wn   = wv & 3;            // 0..3  (N quarter)
    const int n0   = lane & 15;
    const int quad = lane >> 4;
    const int pb   = blockIdx.x * PTS_A;
    const int rowB = wm * 64;
    const int colB = wn * 64;

    {   // embedding: 4096 contiguous fp32 per block -> bf16 cols 0..31
        int g0 = blockIdx.x * 4096 + tid * 8;
        int r = tid >> 2, c8 = (tid & 3) * 8;
        float4 f0 = *(const float4*)(emb + g0);
        float4 f1 = *(const float4*)(emb + g0 + 4);
        ushort_t v8[8];
        v8[0] = f2bc(f0.x); v8[1] = f2bc(f0.y); v8[2] = f2bc(f0.z); v8[3] = f2bc(f0.w);
        v8[4] = f2bc(f1.x); v8[5] = f2bc(f1.y); v8[6] = f2bc(f1.z); v8[7] = f2bc(f1.w);
        *(uint4*)&sFeat[r][c8] = *(uint4*)v8;
    }
    if (tid < 128) {   // dists -> PE(dist,L=2) cols 32..43; zero 44..63; sWn via shfl
        int gr = pb * KNBR + tid;
        float x = dists[gr * 3 + 0];
        float y = dists[gr * 3 + 1];
        float z = dists[gr * 3 + 2];
        float d2 = x * x + y * y + z * z;
        float wraw = (float)mask[gr] / fmaxf(d2, 1e-8f);
        float xs[3] = {x, y, z};
        #pragma unroll
        for (int d = 0; d < 3; d++) {
            #pragma unroll
            for (int l = 0; l < 2; l++) {
                float ang = xs[d] * (float)(1 << l);
                sFeat[tid][32 + d * 4 + l]     = f2bc(__sinf(ang));
                sFeat[tid][32 + d * 4 + 2 + l] = f2bc(__cosf(ang));
            }
        }
        #pragma unroll
        for (int c = 44; c < 64; c++) sFeat[tid][c] = 0;

        // per-point weight normalization: 8-lane shfl tree (r2-validated)
        float gs = wraw;
        gs += __shfl_xor(gs, 1);
        gs += __shfl_xor(gs, 2);
        gs += __shfl_xor(gs, 4);
        sWn[tid] = wraw / fmaxf(gs, 1e-8f);
    }
    __syncthreads();   // B1

    f32x4 acc[16];
    #pragma unroll
    for (int i = 0; i < 16; i++) acc[i] = (f32x4){0.f, 0.f, 0.f, 0.f};

    // ---- layer 1: K=64 (44 real) ----
    #pragma unroll
    for (int ki = 0; ki < 2; ki++) {
        bf16x8 a[4];
        #pragma unroll
        for (int mt = 0; mt < 4; mt++)
            a[mt] = *(const bf16x8*)&sFeat[rowB + mt * 16 + n0][ki * 32 + quad * 8];
        const ushort_t* bp = ws + W1S_OFF + ki * 8192 + quad * 2048 + (colB + n0) * 8;
        #pragma unroll
        for (int nt = 0; nt < 4; nt++) {
            bf16x8 b = *(const bf16x8*)(bp + nt * 128);
            #pragma unroll
            for (int mt = 0; mt < 4; mt++)
                acc[mt * 4 + nt] = __builtin_amdgcn_mfma_f32_16x16x32_bf16(a[mt], b, acc[mt * 4 + nt], 0, 0, 0);
        }
    }

    // ---- bias+relu IN REGISTERS, pre-barrier (no LDS dependency):
    //      overlaps other waves' layer-1 MFMA tails + barrier drain.
    #pragma unroll
    for (int nt = 0; nt < 4; nt++) {
        float bias = b1[colB + nt * 16 + n0];
        #pragma unroll
        for (int mt = 0; mt < 4; mt++)
            #pragma unroll
            for (int r = 0; r < 4; r++)
                acc[mt * 4 + nt][r] = fmaxf(acc[mt * 4 + nt][r] + bias, 0.f);
    }
    __syncthreads();   // B2: all sFeat reads complete before sH1 overwrite

    {   // epilogue 1 (pure cvt + ds_write): -> sH1 (overwrites sFeat region)
        #pragma unroll
        for (int nt = 0; nt < 4; nt++) {
            int col = colB + nt * 16 + n0;
            #pragma unroll
            for (int mt = 0; mt < 4; mt++)
                #pragma unroll
                for (int r = 0; r < 4; r++)
                    sH1[rowB + mt * 16 + quad * 4 + r][col] = f2bc(acc[mt * 4 + nt][r]);
        }
    }

    // ---- layer 2 (early): own k-tiles ki = 2wn, 2wn+1, pre-barrier.
    //      Reads only rows rowB..+63 x cols colB..+63 — data THIS wave
    //      just wrote; intra-wave ds ordering (lgkmcnt) makes it safe.
    f32x4 acc2[16];
    #pragma unroll
    for (int i = 0; i < 16; i++) acc2[i] = (f32x4){0.f, 0.f, 0.f, 0.f};
    #pragma unroll
    for (int kio = 0; kio < 2; kio++) {
        int ki = 2 * wn + kio;          // wave-uniform
        bf16x8 a[4];
        #pragma unroll
        for (int mt = 0; mt < 4; mt++)
            a[mt] = *(const bf16x8*)&sH1[rowB + mt * 16 + n0][ki * 32 + quad * 8];
        const ushort_t* bp = ws + W2S_OFF + ki * 8192 + quad * 2048 + (colB + n0) * 8;
        #pragma unroll
        for (int nt = 0; nt < 4; nt++) {
            bf16x8 b = *(const bf16x8*)(bp + nt * 128);
            #pragma unroll
            for (int mt = 0; mt < 4; mt++)
                acc2[mt * 4 + nt] = __builtin_amdgcn_mfma_f32_16x16x32_bf16(a[mt], b, acc2[mt * 4 + nt], 0, 0, 0);
        }
    }

    // hoist epi-2 bias loads above the barrier (independent global loads)
    float b2v[4];
    #pragma unroll
    for (int nt = 0; nt < 4; nt++) b2v[nt] = b2[colB + nt * 16 + n0];
    __syncthreads();   // B3

    // ---- layer 2 (rest): remaining 6 k-tiles ----
    #pragma unroll
    for (int ki2 = 0; ki2 < 6; ki2++) {
        int ki = ki2 + ((ki2 >= 2 * wn) ? 2 : 0);   // skip own pair
        bf16x8 a[4];
        #pragma unroll
        for (int mt = 0; mt < 4; mt++)
            a[mt] = *(const bf16x8*)&sH1[rowB + mt * 16 + n0][ki * 32 + quad * 8];
        const ushort_t* bp = ws + W2S_OFF + ki * 8192 + quad * 2048 + (colB + n0) * 8;
        #pragma unroll
        for (int nt = 0; nt < 4; nt++) {
            bf16x8 b = *(const bf16x8*)(bp + nt * 128);
            #pragma unroll
            for (int mt = 0; mt < 4; mt++)
                acc2[mt * 4 + nt] = __builtin_amdgcn_mfma_f32_16x16x32_bf16(a[mt], b, acc2[mt * 4 + nt], 0, 0, 0);
        }
    }
    {   // epilogue 2: relu + neighbor-weighted sum -> global agg (bf16)
        #pragma unroll
        for (int mt = 0; mt < 4; mt++) {
            f32x4 wn4 = *(const f32x4*)&sWn[rowB + mt * 16 + quad * 4];
            #pragma unroll
            for (int nt = 0; nt < 4; nt++) {
                int col = colB + nt * 16 + n0;
                float bias = b2v[nt];
                float s = fmaxf(acc2[mt * 4 + nt][0] + bias, 0.f) * wn4[0]
                        + fmaxf(acc2[mt * 4 + nt][1] + bias, 0.f) * wn4[1]
                        + fmaxf(acc2[mt * 4 + nt][2] + bias, 0.f) * wn4[2]
                        + fmaxf(acc2[mt * 4 + nt][3] + bias, 0.f) * wn4[3];
                s += __shfl_xor(s, 16);
                if ((quad & 1) == 0) {
                    int pt = pb + 8 * wm + 2 * mt + (quad >> 1);
                    aggg[(size_t)pt * 256 + col] = f2bc(s);
                }
            }
        }
    }
}

// ------------------------------------------------------------------
// kernel B: branch MLPs, 32 points / block, 4 waves. Hidden layers
// N-split; final 256->{1,3} projections done with MFMA against
// pre-swizzled wa2/wc2 (N=16 pad). sAh aliases dead sCin.
// (round-0 verbatim; measured contribution ~30 us — not a lever)
// ------------------------------------------------------------------
__global__ __launch_bounds__(256) void pa_branch(
    const float* __restrict__ vdirs,
    const float* __restrict__ ba1v, const float* __restrict__ ba2v,
    const float* __restrict__ bc1v, const float* __restrict__ bc2v,
    const ushort_t* __restrict__ ws, const ushort_t* __restrict__ aggg,
    float* __restrict__ out)
{
    __shared__ __align__(16) ushort_t reg1[32 * 296];  // sCin; later sAh[32][264]
    __shared__ __align__(16) ushort_t reg2[32 * 264];  // sCh
    ushort_t (*sCin)[296] = (ushort_t(*)[296])reg1;
    ushort_t (*sAh)[264]  = (ushort_t(*)[264])reg1;
    ushort_t (*sCh)[264]  = (ushort_t(*)[264])reg2;

    const int tid  = threadIdx.x;
    const int lane = tid & 63;
    const int wv   = tid >> 6;
    const int n0   = lane & 15;
    const int quad = lane >> 4;
    const int pb   = blockIdx.x * PTS_B;
    const int colB = wv * 64;

    // ---- staging ----
    #pragma unroll
    for (int it = 0; it < 4; it++) {   // agg: 32*256 = 8192 ushorts
        int idx = (tid + it * 256) * 8;
        uint4 v = *(const uint4*)(aggg + (size_t)pb * 256 + idx);
        *(uint4*)&sCin[idx >> 8][idx & 255] = v;
    }
    #pragma unroll
    for (int it = 0; it < 3; it++) {   // PE(viewdirs,L=4): 32*24 = 768
        int t = tid + it * 256;
        int p = t / 24, j = t % 24;
        int d = j >> 3, jj = j & 7, l = jj & 3, isc = jj >> 2;
        float ang = vdirs[(pb + p) * 3 + d] * (float)(1 << l);
        sCin[p][256 + j] = f2bc(isc ? __cosf(ang) : __sinf(ang));
    }
    sCin[tid >> 3][280 + (tid & 7)] = 0;   // K-pad cols
    __syncthreads();

    f32x4 accA[8], accC[8];   // [mt 0..1][nt 0..3]
    #pragma unroll
    for (int i = 0; i < 8; i++) { accA[i] = (f32x4){0.f, 0.f, 0.f, 0.f}; accC[i] = accA[i]; }

    // ---- alpha hidden: K=256 ----
    #pragma unroll
    for (int ki = 0; ki < 8; ki++) {
        bf16x8 a0 = *(const bf16x8*)&sCin[n0][ki * 32 + quad * 8];
        bf16x8 a1 = *(const bf16x8*)&sCin[16 + n0][ki * 32 + quad * 8];
        const ushort_t* bp = ws + WA1S_OFF + ki * 8192 + quad * 2048 + (colB + n0) * 8;
        #pragma unroll
        for (int nt = 0; nt < 4; nt++) {
            bf16x8 b = *(const bf16x8*)(bp + nt * 128);
            accA[nt]     = __builtin_amdgcn_mfma_f32_16x16x32_bf16(a0, b, accA[nt], 0, 0, 0);
            accA[4 + nt] = __builtin_amdgcn_mfma_f32_16x16x32_bf16(a1, b, accA[4 + nt], 0, 0, 0);
        }
    }
    // ---- color hidden: K=288 (280 real) ----
    #pragma unroll
    for (int ki = 0; ki < 9; ki++) {
        bf16x8 a0 = *(const bf16x8*)&sCin[n0][ki * 32 + quad * 8];
        bf16x8 a1 = *(const bf16x8*)&sCin[16 + n0][ki * 32 + quad * 8];
        const ushort_t* bp = ws + WC1S_OFF + ki * 8192 + quad * 2048 + (colB + n0) * 8;
        #pragma unroll
        for (int nt = 0; nt < 4; nt++) {
            bf16x8 b = *(const bf16x8*)(bp + nt * 128);
            accC[nt]     = __builtin_amdgcn_mfma_f32_16x16x32_bf16(a0, b, accC[nt], 0, 0, 0);
            accC[4 + nt] = __builtin_amdgcn_mfma_f32_16x16x32_bf16(a1, b, accC[4 + nt], 0, 0, 0);
        }
    }
    __syncthreads();   // all sCin reads complete before sAh overwrites it

    #pragma unroll
    for (int nt = 0; nt < 4; nt++) {
        int col = colB + nt * 16 + n0;
        float biasA = ba1v[col];
        float biasC = bc1v[col];
        #pragma unroll
        for (int mt = 0; mt < 2; mt++)
            #pragma unroll
            for (int r = 0; r < 4; r++) {
                int row = mt * 16 + quad * 4 + r;
                sAh[row][col] = f2bc(fmaxf(accA[mt * 4 + nt][r] + biasA, 0.f));
                sCh[row][col] = f2bc(fmaxf(accC[mt * 4 + nt][r] + biasC, 0.f));
            }
    }
    __syncthreads();

    // ---- finals via MFMA: wave0/1 alpha m-tiles, wave2/3 color m-tiles ----
    {
        const int isColor = wv >> 1;
        const int baseM   = (wv & 1) * 16;
        const ushort_t* A = isColor ? &sCh[0][0] : &sAh[0][0];
        const ushort_t* B = ws + (isColor ? WC2S_OFF : WA2S_OFF);
        f32x4 acc4 = (f32x4){0.f, 0.f, 0.f, 0.f};
        #pragma unroll
        for (int ki = 0; ki < 8; ki++) {
            bf16x8 a = *(const bf16x8*)(A + (baseM + n0) * 264 + ki * 32 + quad * 8);
            bf16x8 b = *(const bf16x8*)(B + ki * 512 + quad * 128 + n0 * 8);
            acc4 = __builtin_amdgcn_mfma_f32_16x16x32_bf16(a, b, acc4, 0, 0, 0);
        }
        if (!isColor) {
            if (n0 == 0) {
                float ba2s = ba2v[0];
                #pragma unroll
                for (int r = 0; r < 4; r++) {
                    int gp = pb + baseM + quad * 4 + r;
                    float yv = acc4[r] + ba2s - 1.0f;
                    out[(size_t)gp * 4] = (yv > 20.f) ? yv : log1pf(expf(yv));
                }
            }
        } else {
            if (n0 < 3) {
                float bc2s = bc2v[n0];
                #pragma unroll
                for (int r = 0; r < 4; r++) {
                    int gp = pb + baseM + quad * 4 + r;
                    float sig = 1.f / (1.f + expf(-(acc4[r] + bc2s)));
                    out[(size_t)gp * 4 + 1 + n0] = sig * (1.0f + 2e-3f) - 1e-3f;
                }
            }
        }
    }
}

extern "C" void kernel_launch(void* const* d_in, const int* in_sizes, int n_in,
                              void* d_out, int out_size, void* d_ws, size_t ws_size,
                              hipStream_t stream) {
    const float* emb   = (const float*)d_in[0];
    const float* dists = (const float*)d_in[1];
    const float* vdir  = (const float*)d_in[2];
    const int*   mask  = (const int*)d_in[3];
    const float* w1    = (const float*)d_in[4];
    const float* b1    = (const float*)d_in[5];
    const float* w2    = (const float*)d_in[6];
    const float* b2    = (const float*)d_in[7];
    const float* wa1   = (const float*)d_in[8];
    const float* ba1   = (const float*)d_in[9];
    const float* wa2   = (const float*)d_in[10];
    const float* ba2   = (const float*)d_in[11];
    const float* wc1   = (const float*)d_in[12];
    const float* bc1   = (const float*)d_in[13];
    const float* wc2   = (const float*)d_in[14];
    const float* bc2   = (const float*)d_in[15];
    ushort_t* ws  = (ushort_t*)d_ws;
    float*    out = (float*)d_out;

    prep_swizzle<<<dim3((WS_WEIGHT + 255) / 256), dim3(256), 0, stream>>>(
        w1, w2, wa1, wc1, wa2, wc2, ws);
    pa_mlp<<<dim3(NBLK_A), dim3(512), 0, stream>>>(
        emb, dists, mask, b1, b2, ws, ws + AGG_OFF);
    pa_branch<<<dim3(NBLK_B), dim3(256), 0, stream>>>(
        vdir, ba1, ba2, bc1, bc2, ws, ws + AGG_OFF, out);
}

// Round 13
// 198.404 us; speedup vs baseline: 1.0051x; 1.0051x over previous
//
#include <hip/hip_runtime.h>

typedef unsigned short ushort_t;
typedef __bf16 bf16x8 __attribute__((ext_vector_type(8)));
typedef float f32x4 __attribute__((ext_vector_type(4)));

// ---- problem constants ----
#define NPTS   49152     // B*R*SR
#define KNBR   8
#define PTS_A  16        // points per block, kernel A -> 128 neighbor rows
#define NBLK_A (NPTS / PTS_A)    // 3072
#define PTS_B  32        // points per block, kernel B
#define NBLK_B (NPTS / PTS_B)    // 1536

// ---- workspace layout (ushort elements) ----
// big weights: Wswz[(k/8)*256*8 + n*8 + (k%8)], K zero-padded
// final weights (N=16 pad): Wf[(k/8)*16*8 + n*8 + (k%8)], K=256
#define W1S_OFF   0         // K=44 ->64
#define W2S_OFF   16384     // K=256
#define WA1S_OFF  81920     // K=256
#define WC1S_OFF  147456    // K=280 ->288
#define WA2S_OFF  221184    // 4096 (wa2 in col 0)
#define WC2S_OFF  225280    // 4096 (wc2 in cols 0..2)
#define WS_WEIGHT 229376
#define AGG_OFF   229376    // agg[49152][256] bf16 = 12.58M ushorts (25.2 MB)

__device__ __forceinline__ float b2f(ushort_t u) {
    return __builtin_bit_cast(float, ((unsigned)u) << 16);
}
// RNE f2b (prep only, cold path)
__device__ __forceinline__ ushort_t f2b(float f) {
    unsigned x = __builtin_bit_cast(unsigned, f);
    unsigned r = x + 0x7fffu + ((x >> 16) & 1u);
    return (ushort_t)(r >> 16);
}
// cheap round-half-up f2b (2 VALU ops, hot path)
__device__ __forceinline__ ushort_t f2bc(float f) {
    unsigned x = __builtin_bit_cast(unsigned, f);
    return (ushort_t)((x + 0x8000u) >> 16);
}

// ------------------------------------------------------------------
// prep: swizzle fp32 weights into bf16 MFMA-B fragment order.
// (round-0 verbatim)
// ------------------------------------------------------------------
__global__ __launch_bounds__(256) void prep_swizzle(
    const float* __restrict__ w1, const float* __restrict__ w2,
    const float* __restrict__ wa1, const float* __restrict__ wc1,
    const float* __restrict__ wa2, const float* __restrict__ wc2,
    ushort_t* __restrict__ ws)
{
    int idx = blockIdx.x * 256 + threadIdx.x;
    if (idx >= WS_WEIGHT) return;

    if (idx >= WA2S_OFF) {   // final-projection matrices, N=16 pad
        int off2 = idx - WA2S_OFF;
        int mat = off2 >> 12;          // 0: wa2, 1: wc2
        int off = off2 & 4095;
        int kb = off >> 7, rem = off & 127;
        int n = rem >> 3, j = rem & 7;
        int k = kb * 8 + j;
        float v = 0.f;
        if (mat == 0) { if (n == 0) v = wa2[k]; }
        else          { if (n < 3)  v = wc2[k * 3 + n]; }
        ws[idx] = f2b(v);
        return;
    }

    const float* src; int off, srcK, base;
    if (idx < W2S_OFF)        { src = w1;  base = W1S_OFF;  off = idx - W1S_OFF;  srcK = 44;  }
    else if (idx < WA1S_OFF)  { src = w2;  base = W2S_OFF;  off = idx - W2S_OFF;  srcK = 256; }
    else if (idx < WC1S_OFF)  { src = wa1; base = WA1S_OFF; off = idx - WA1S_OFF; srcK = 256; }
    else                      { src = wc1; base = WC1S_OFF; off = idx - WC1S_OFF; srcK = 280; }
    int kb  = off >> 11;          // /(256*8)
    int rem = off & 2047;
    int j = rem >> 8;             // k%8
    int n = rem & 255;
    int k = kb * 8 + j;
    float v = (k < srcK) ? src[k * 256 + n] : 0.f;
    ws[base + kb * 2048 + n * 8 + j] = f2b(v);
}

// ------------------------------------------------------------------
// kernel A: per-neighbor MLP (44->256->256) + weighted aggregation.
// Round-11 structure VERBATIM (best measured: pa_mlp ~76us, total 198.0;
// r12's bundled register-lifetime edits spilled ~16MB scratch and
// regressed — reverted). Single addition: s_setprio(1) around MFMA
// clusters (T5). With 2 independent blocks/CU at skewed phases plus the
// early-k role diversity, MFMA-phase waves win issue arbitration over
// staging/epilogue waves (m191 mechanism; SALU-only, zero VGPR cost).
// ------------------------------------------------------------------
__global__ __launch_bounds__(512, 4) void pa_mlp(
    const float* __restrict__ emb, const float* __restrict__ dists,
    const int* __restrict__ mask,  const float* __restrict__ b1,
    const float* __restrict__ b2,  const ushort_t* __restrict__ ws,
    ushort_t* __restrict__ aggg)
{
    __shared__ __align__(16) ushort_t uH1[128 * 264];  // phase1: sFeat[128][72]; phase2: sH1[128][264]
    __shared__ __align__(16) float sWraw[128];
    __shared__ __align__(16) float sWn[128];
    ushort_t (*sFeat)[72] = (ushort_t(*)[72])uH1;
    ushort_t (*sH1)[264]  = (ushort_t(*)[264])uH1;

    const int tid  = threadIdx.x;
    const int lane = tid & 63;
    const int wv   = tid >> 6;          // 0..7
    const int wm   = wv >> 2;           // 0..1  (M half: rows 0..63 / 64..127)
    const int wn   = wv & 3;            // 0..3  (N quarter)
    const int n0   = lane & 15;
    const int quad = lane >> 4;
    const int pb   = blockIdx.x * PTS_A;
    const int rowB = wm * 64;
    const int colB = wn * 64;

    {   // embedding: 4096 contiguous fp32 per block -> bf16 cols 0..31
        int g0 = blockIdx.x * 4096 + tid * 8;
        int r = tid >> 2, c8 = (tid & 3) * 8;
        float4 f0 = *(const float4*)(emb + g0);
        float4 f1 = *(const float4*)(emb + g0 + 4);
        ushort_t v8[8];
        v8[0] = f2bc(f0.x); v8[1] = f2bc(f0.y); v8[2] = f2bc(f0.z); v8[3] = f2bc(f0.w);
        v8[4] = f2bc(f1.x); v8[5] = f2bc(f1.y); v8[6] = f2bc(f1.z); v8[7] = f2bc(f1.w);
        *(uint4*)&sFeat[r][c8] = *(uint4*)v8;
    }
    if (tid < 128) {   // dists -> raw weight + PE(dist,L=2) cols 32..43; zero 44..63
        int gr = pb * KNBR + tid;
        float x = dists[gr * 3 + 0];
        float y = dists[gr * 3 + 1];
        float z = dists[gr * 3 + 2];
        float d2 = x * x + y * y + z * z;
        sWraw[tid] = (float)mask[gr] / fmaxf(d2, 1e-8f);
        float xs[3] = {x, y, z};
        #pragma unroll
        for (int d = 0; d < 3; d++) {
            #pragma unroll
            for (int l = 0; l < 2; l++) {
                float ang = xs[d] * (float)(1 << l);
                sFeat[tid][32 + d * 4 + l]     = f2bc(__sinf(ang));
                sFeat[tid][32 + d * 4 + 2 + l] = f2bc(__cosf(ang));
            }
        }
        #pragma unroll
        for (int c = 44; c < 64; c++) sFeat[tid][c] = 0;
    }
    __syncthreads();
    if (tid < 128) {
        int lp = tid >> 3;
        float s = 0.f;
        #pragma unroll
        for (int k = 0; k < 8; k++) s += sWraw[lp * 8 + k];
        sWn[tid] = sWraw[tid] / fmaxf(s, 1e-8f);
    }

    f32x4 acc[16];
    #pragma unroll
    for (int i = 0; i < 16; i++) acc[i] = (f32x4){0.f, 0.f, 0.f, 0.f};

    // ---- layer 1: K=64 (44 real) ----
    __builtin_amdgcn_s_setprio(1);
    #pragma unroll
    for (int ki = 0; ki < 2; ki++) {
        bf16x8 a[4];
        #pragma unroll
        for (int mt = 0; mt < 4; mt++)
            a[mt] = *(const bf16x8*)&sFeat[rowB + mt * 16 + n0][ki * 32 + quad * 8];
        const ushort_t* bp = ws + W1S_OFF + ki * 8192 + quad * 2048 + (colB + n0) * 8;
        #pragma unroll
        for (int nt = 0; nt < 4; nt++) {
            bf16x8 b = *(const bf16x8*)(bp + nt * 128);
            #pragma unroll
            for (int mt = 0; mt < 4; mt++)
                acc[mt * 4 + nt] = __builtin_amdgcn_mfma_f32_16x16x32_bf16(a[mt], b, acc[mt * 4 + nt], 0, 0, 0);
        }
    }
    __builtin_amdgcn_s_setprio(0);
    __syncthreads();

    {   // epilogue 1: bias+relu -> sH1 (overwrites sFeat region)
        #pragma unroll
        for (int nt = 0; nt < 4; nt++) {
            int col = colB + nt * 16 + n0;
            float bias = b1[col];
            #pragma unroll
            for (int mt = 0; mt < 4; mt++)
                #pragma unroll
                for (int r = 0; r < 4; r++)
                    sH1[rowB + mt * 16 + quad * 4 + r][col] = f2bc(fmaxf(acc[mt * 4 + nt][r] + bias, 0.f));
        }
    }

    // ---- layer 2 (early): own k-tiles ki = 2wn, 2wn+1, pre-barrier.
    //      Reads only rows rowB..+63 x cols colB..+63 — data THIS wave
    //      just wrote; intra-wave ds ordering (lgkmcnt) makes it safe.
    f32x4 acc2[16];
    #pragma unroll
    for (int i = 0; i < 16; i++) acc2[i] = (f32x4){0.f, 0.f, 0.f, 0.f};
    __builtin_amdgcn_s_setprio(1);
    #pragma unroll
    for (int kio = 0; kio < 2; kio++) {
        int ki = 2 * wn + kio;          // wave-uniform
        bf16x8 a[4];
        #pragma unroll
        for (int mt = 0; mt < 4; mt++)
            a[mt] = *(const bf16x8*)&sH1[rowB + mt * 16 + n0][ki * 32 + quad * 8];
        const ushort_t* bp = ws + W2S_OFF + ki * 8192 + quad * 2048 + (colB + n0) * 8;
        #pragma unroll
        for (int nt = 0; nt < 4; nt++) {
            bf16x8 b = *(const bf16x8*)(bp + nt * 128);
            #pragma unroll
            for (int mt = 0; mt < 4; mt++)
                acc2[mt * 4 + nt] = __builtin_amdgcn_mfma_f32_16x16x32_bf16(a[mt], b, acc2[mt * 4 + nt], 0, 0, 0);
        }
    }
    __builtin_amdgcn_s_setprio(0);
    __syncthreads();

    // ---- layer 2 (rest): remaining 6 k-tiles ----
    __builtin_amdgcn_s_setprio(1);
    #pragma unroll
    for (int ki2 = 0; ki2 < 6; ki2++) {
        int ki = ki2 + ((ki2 >= 2 * wn) ? 2 : 0);   // skip own pair
        bf16x8 a[4];
        #pragma unroll
        for (int mt = 0; mt < 4; mt++)
            a[mt] = *(const bf16x8*)&sH1[rowB + mt * 16 + n0][ki * 32 + quad * 8];
        const ushort_t* bp = ws + W2S_OFF + ki * 8192 + quad * 2048 + (colB + n0) * 8;
        #pragma unroll
        for (int nt = 0; nt < 4; nt++) {
            bf16x8 b = *(const bf16x8*)(bp + nt * 128);
            #pragma unroll
            for (int mt = 0; mt < 4; mt++)
                acc2[mt * 4 + nt] = __builtin_amdgcn_mfma_f32_16x16x32_bf16(a[mt], b, acc2[mt * 4 + nt], 0, 0, 0);
        }
    }
    __builtin_amdgcn_s_setprio(0);
    {   // epilogue 2: relu + neighbor-weighted sum -> global agg (bf16)
        #pragma unroll
        for (int mt = 0; mt < 4; mt++) {
            f32x4 wn4 = *(const f32x4*)&sWn[rowB + mt * 16 + quad * 4];
            #pragma unroll
            for (int nt = 0; nt < 4; nt++) {
                int col = colB + nt * 16 + n0;
                float bias = b2[col];
                float s = fmaxf(acc2[mt * 4 + nt][0] + bias, 0.f) * wn4[0]
                        + fmaxf(acc2[mt * 4 + nt][1] + bias, 0.f) * wn4[1]
                        + fmaxf(acc2[mt * 4 + nt][2] + bias, 0.f) * wn4[2]
                        + fmaxf(acc2[mt * 4 + nt][3] + bias, 0.f) * wn4[3];
                s += __shfl_xor(s, 16);
                if ((quad & 1) == 0) {
                    int pt = pb + 8 * wm + 2 * mt + (quad >> 1);
                    aggg[(size_t)pt * 256 + col] = f2bc(s);
                }
            }
        }
    }
}

// ------------------------------------------------------------------
// kernel B: branch MLPs, 32 points / block, 4 waves. Hidden layers
// N-split; final 256->{1,3} projections done with MFMA against
// pre-swizzled wa2/wc2 (N=16 pad). sAh aliases dead sCin.
// (round-0 verbatim + setprio around hidden MFMA loops; 4 blocks/CU
// at independent phases — the T5-favorable regime)
// ------------------------------------------------------------------
__global__ __launch_bounds__(256) void pa_branch(
    const float* __restrict__ vdirs,
    const float* __restrict__ ba1v, const float* __restrict__ ba2v,
    const float* __restrict__ bc1v, const float* __restrict__ bc2v,
    const ushort_t* __restrict__ ws, const ushort_t* __restrict__ aggg,
    float* __restrict__ out)
{
    __shared__ __align__(16) ushort_t reg1[32 * 296];  // sCin; later sAh[32][264]
    __shared__ __align__(16) ushort_t reg2[32 * 264];  // sCh
    ushort_t (*sCin)[296] = (ushort_t(*)[296])reg1;
    ushort_t (*sAh)[264]  = (ushort_t(*)[264])reg1;
    ushort_t (*sCh)[264]  = (ushort_t(*)[264])reg2;

    const int tid  = threadIdx.x;
    const int lane = tid & 63;
    const int wv   = tid >> 6;
    const int n0   = lane & 15;
    const int quad = lane >> 4;
    const int pb   = blockIdx.x * PTS_B;
    const int colB = wv * 64;

    // ---- staging ----
    #pragma unroll
    for (int it = 0; it < 4; it++) {   // agg: 32*256 = 8192 ushorts
        int idx = (tid + it * 256) * 8;
        uint4 v = *(const uint4*)(aggg + (size_t)pb * 256 + idx);
        *(uint4*)&sCin[idx >> 8][idx & 255] = v;
    }
    #pragma unroll
    for (int it = 0; it < 3; it++) {   // PE(viewdirs,L=4): 32*24 = 768
        int t = tid + it * 256;
        int p = t / 24, j = t % 24;
        int d = j >> 3, jj = j & 7, l = jj & 3, isc = jj >> 2;
        float ang = vdirs[(pb + p) * 3 + d] * (float)(1 << l);
        sCin[p][256 + j] = f2bc(isc ? __cosf(ang) : __sinf(ang));
    }
    sCin[tid >> 3][280 + (tid & 7)] = 0;   // K-pad cols
    __syncthreads();

    f32x4 accA[8], accC[8];   // [mt 0..1][nt 0..3]
    #pragma unroll
    for (int i = 0; i < 8; i++) { accA[i] = (f32x4){0.f, 0.f, 0.f, 0.f}; accC[i] = accA[i]; }

    // ---- alpha hidden: K=256 ----
    __builtin_amdgcn_s_setprio(1);
    #pragma unroll
    for (int ki = 0; ki < 8; ki++) {
        bf16x8 a0 = *(const bf16x8*)&sCin[n0][ki * 32 + quad * 8];
        bf16x8 a1 = *(const bf16x8*)&sCin[16 + n0][ki * 32 + quad * 8];
        const ushort_t* bp = ws + WA1S_OFF + ki * 8192 + quad * 2048 + (colB + n0) * 8;
        #pragma unroll
        for (int nt = 0; nt < 4; nt++) {
            bf16x8 b = *(const bf16x8*)(bp + nt * 128);
            accA[nt]     = __builtin_amdgcn_mfma_f32_16x16x32_bf16(a0, b, accA[nt], 0, 0, 0);
            accA[4 + nt] = __builtin_amdgcn_mfma_f32_16x16x32_bf16(a1, b, accA[4 + nt], 0, 0, 0);
        }
    }
    // ---- color hidden: K=288 (280 real) ----
    #pragma unroll
    for (int ki = 0; ki < 9; ki++) {
        bf16x8 a0 = *(const bf16x8*)&sCin[n0][ki * 32 + quad * 8];
        bf16x8 a1 = *(const bf16x8*)&sCin[16 + n0][ki * 32 + quad * 8];
        const ushort_t* bp = ws + WC1S_OFF + ki * 8192 + quad * 2048 + (colB + n0) * 8;
        #pragma unroll
        for (int nt = 0; nt < 4; nt++) {
            bf16x8 b = *(const bf16x8*)(bp + nt * 128);
            accC[nt]     = __builtin_amdgcn_mfma_f32_16x16x32_bf16(a0, b, accC[nt], 0, 0, 0);
            accC[4 + nt] = __builtin_amdgcn_mfma_f32_16x16x32_bf16(a1, b, accC[4 + nt], 0, 0, 0);
        }
    }
    __builtin_amdgcn_s_setprio(0);
    __syncthreads();   // all sCin reads complete before sAh overwrites it

    #pragma unroll
    for (int nt = 0; nt < 4; nt++) {
        int col = colB + nt * 16 + n0;
        float biasA = ba1v[col];
        float biasC = bc1v[col];
        #pragma unroll
        for (int mt = 0; mt < 2; mt++)
            #pragma unroll
            for (int r = 0; r < 4; r++) {
                int row = mt * 16 + quad * 4 + r;
                sAh[row][col] = f2bc(fmaxf(accA[mt * 4 + nt][r] + biasA, 0.f));
                sCh[row][col] = f2bc(fmaxf(accC[mt * 4 + nt][r] + biasC, 0.f));
            }
    }
    __syncthreads();

    // ---- finals via MFMA: wave0/1 alpha m-tiles, wave2/3 color m-tiles ----
    {
        const int isColor = wv >> 1;
        const int baseM   = (wv & 1) * 16;
        const ushort_t* A = isColor ? &sCh[0][0] : &sAh[0][0];
        const ushort_t* B = ws + (isColor ? WC2S_OFF : WA2S_OFF);
        f32x4 acc4 = (f32x4){0.f, 0.f, 0.f, 0.f};
        #pragma unroll
        for (int ki = 0; ki < 8; ki++) {
            bf16x8 a = *(const bf16x8*)(A + (baseM + n0) * 264 + ki * 32 + quad * 8);
            bf16x8 b = *(const bf16x8*)(B + ki * 512 + quad * 128 + n0 * 8);
            acc4 = __builtin_amdgcn_mfma_f32_16x16x32_bf16(a, b, acc4, 0, 0, 0);
        }
        if (!isColor) {
            if (n0 == 0) {
                float ba2s = ba2v[0];
                #pragma unroll
                for (int r = 0; r < 4; r++) {
                    int gp = pb + baseM + quad * 4 + r;
                    float yv = acc4[r] + ba2s - 1.0f;
                    out[(size_t)gp * 4] = (yv > 20.f) ? yv : log1pf(expf(yv));
                }
            }
        } else {
            if (n0 < 3) {
                float bc2s = bc2v[n0];
                #pragma unroll
                for (int r = 0; r < 4; r++) {
                    int gp = pb + baseM + quad * 4 + r;
                    float sig = 1.f / (1.f + expf(-(acc4[r] + bc2s)));
                    out[(size_t)gp * 4 + 1 + n0] = sig * (1.0f + 2e-3f) - 1e-3f;
                }
            }
        }
    }
}

extern "C" void kernel_launch(void* const* d_in, const int* in_sizes, int n_in,
                              void* d_out, int out_size, void* d_ws, size_t ws_size,
                              hipStream_t stream) {
    const float* emb   = (const float*)d_in[0];
    const float* dists = (const float*)d_in[1];
    const float* vdir  = (const float*)d_in[2];
    const int*   mask  = (const int*)d_in[3];
    const float* w1    = (const float*)d_in[4];
    const float* b1    = (const float*)d_in[5];
    const float* w2    = (const float*)d_in[6];
    const float* b2    = (const float*)d_in[7];
    const float* wa1   = (const float*)d_in[8];
    const float* ba1   = (const float*)d_in[9];
    const float* wa2   = (const float*)d_in[10];
    const float* ba2   = (const float*)d_in[11];
    const float* wc1   = (const float*)d_in[12];
    const float* bc1   = (const float*)d_in[13];
    const float* wc2   = (const float*)d_in[14];
    const float* bc2   = (const float*)d_in[15];
    ushort_t* ws  = (ushort_t*)d_ws;
    float*    out = (float*)d_out;

    prep_swizzle<<<dim3((WS_WEIGHT + 255) / 256), dim3(256), 0, stream>>>(
        w1, w2, wa1, wc1, wa2, wc2, ws);
    pa_mlp<<<dim3(NBLK_A), dim3(512), 0, stream>>>(
        emb, dists, mask, b1, b2, ws, ws + AGG_OFF);
    pa_branch<<<dim3(NBLK_B), dim3(256), 0, stream>>>(
        vdir, ba1, ba2, bc1, bc2, ws, ws + AGG_OFF, out);
}

// Round 14
// 195.133 us; speedup vs baseline: 1.0219x; 1.0168x over previous
//
#include <hip/hip_runtime.h>

typedef unsigned short ushort_t;
typedef __bf16 bf16x8 __attribute__((ext_vector_type(8)));
typedef float f32x4 __attribute__((ext_vector_type(4)));

// ---- problem constants ----
#define NPTS   49152     // B*R*SR
#define KNBR   8
#define PTS_A  16        // points per block, kernel A -> 128 neighbor rows
#define NBLK_A (NPTS / PTS_A)    // 3072
#define PTS_B  32        // points per block, kernel B
#define NBLK_B (NPTS / PTS_B)    // 1536

// ---- workspace layout (ushort elements) ----
// big weights: Wswz[(k/8)*256*8 + n*8 + (k%8)], K zero-padded
// final weights (N=16 pad): Wf[(k/8)*16*8 + n*8 + (k%8)], K=256
#define W1S_OFF   0         // K=44 ->64
#define W2S_OFF   16384     // K=256
#define WA1S_OFF  81920     // K=256
#define WC1S_OFF  147456    // K=280 ->288
#define WA2S_OFF  221184    // 4096 (wa2 in col 0)
#define WC2S_OFF  225280    // 4096 (wc2 in cols 0..2)
#define WS_WEIGHT 229376
#define AGG_OFF   229376    // agg[49152][256] bf16 = 12.58M ushorts (25.2 MB)

__device__ __forceinline__ float b2f(ushort_t u) {
    return __builtin_bit_cast(float, ((unsigned)u) << 16);
}
// RNE f2b (prep only, cold path)
__device__ __forceinline__ ushort_t f2b(float f) {
    unsigned x = __builtin_bit_cast(unsigned, f);
    unsigned r = x + 0x7fffu + ((x >> 16) & 1u);
    return (ushort_t)(r >> 16);
}
// cheap round-half-up f2b (2 VALU ops, hot path)
__device__ __forceinline__ ushort_t f2bc(float f) {
    unsigned x = __builtin_bit_cast(unsigned, f);
    return (ushort_t)((x + 0x8000u) >> 16);
}

// ------------------------------------------------------------------
// prep: swizzle fp32 weights into bf16 MFMA-B fragment order.
// (round-0 verbatim)
// ------------------------------------------------------------------
__global__ __launch_bounds__(256) void prep_swizzle(
    const float* __restrict__ w1, const float* __restrict__ w2,
    const float* __restrict__ wa1, const float* __restrict__ wc1,
    const float* __restrict__ wa2, const float* __restrict__ wc2,
    ushort_t* __restrict__ ws)
{
    int idx = blockIdx.x * 256 + threadIdx.x;
    if (idx >= WS_WEIGHT) return;

    if (idx >= WA2S_OFF) {   // final-projection matrices, N=16 pad
        int off2 = idx - WA2S_OFF;
        int mat = off2 >> 12;          // 0: wa2, 1: wc2
        int off = off2 & 4095;
        int kb = off >> 7, rem = off & 127;
        int n = rem >> 3, j = rem & 7;
        int k = kb * 8 + j;
        float v = 0.f;
        if (mat == 0) { if (n == 0) v = wa2[k]; }
        else          { if (n < 3)  v = wc2[k * 3 + n]; }
        ws[idx] = f2b(v);
        return;
    }

    const float* src; int off, srcK, base;
    if (idx < W2S_OFF)        { src = w1;  base = W1S_OFF;  off = idx - W1S_OFF;  srcK = 44;  }
    else if (idx < WA1S_OFF)  { src = w2;  base = W2S_OFF;  off = idx - W2S_OFF;  srcK = 256; }
    else if (idx < WC1S_OFF)  { src = wa1; base = WA1S_OFF; off = idx - WA1S_OFF; srcK = 256; }
    else                      { src = wc1; base = WC1S_OFF; off = idx - WC1S_OFF; srcK = 280; }
    int kb  = off >> 11;          // /(256*8)
    int rem = off & 2047;
    int j = rem >> 8;             // k%8
    int n = rem & 255;
    int k = kb * 8 + j;
    float v = (k < srcK) ? src[k * 256 + n] : 0.f;
    ws[base + kb * 2048 + n * 8 + j] = f2b(v);
}

// ------------------------------------------------------------------
// kernel A: per-neighbor MLP (44->256->256) + weighted aggregation.
// ROUND-11 VERBATIM — best measured (pa_mlp ~76us). NO setprio here:
// r13 showed setprio costs ~10us on this kernel (barrier-lockstep
// waves, m190 regime). Own-k-tile early layer-2 start retained: after
// epi-1, wave (wm,wn) runs k-tiles ki=2wn,2wn+1 on its own rows
// pre-barrier (pipe-diverse overlap of MFMA vs other waves' epilogue
// VALU/LDS + barrier drain — the one lever that paid, r11: 84->76).
// ------------------------------------------------------------------
__global__ __launch_bounds__(512, 4) void pa_mlp(
    const float* __restrict__ emb, const float* __restrict__ dists,
    const int* __restrict__ mask,  const float* __restrict__ b1,
    const float* __restrict__ b2,  const ushort_t* __restrict__ ws,
    ushort_t* __restrict__ aggg)
{
    __shared__ __align__(16) ushort_t uH1[128 * 264];  // phase1: sFeat[128][72]; phase2: sH1[128][264]
    __shared__ __align__(16) float sWraw[128];
    __shared__ __align__(16) float sWn[128];
    ushort_t (*sFeat)[72] = (ushort_t(*)[72])uH1;
    ushort_t (*sH1)[264]  = (ushort_t(*)[264])uH1;

    const int tid  = threadIdx.x;
    const int lane = tid & 63;
    const int wv   = tid >> 6;          // 0..7
    const int wm   = wv >> 2;           // 0..1  (M half: rows 0..63 / 64..127)
    const int wn   = wv & 3;            // 0..3  (N quarter)
    const int n0   = lane & 15;
    const int quad = lane >> 4;
    const int pb   = blockIdx.x * PTS_A;
    const int rowB = wm * 64;
    const int colB = wn * 64;

    {   // embedding: 4096 contiguous fp32 per block -> bf16 cols 0..31
        int g0 = blockIdx.x * 4096 + tid * 8;
        int r = tid >> 2, c8 = (tid & 3) * 8;
        float4 f0 = *(const float4*)(emb + g0);
        float4 f1 = *(const float4*)(emb + g0 + 4);
        ushort_t v8[8];
        v8[0] = f2bc(f0.x); v8[1] = f2bc(f0.y); v8[2] = f2bc(f0.z); v8[3] = f2bc(f0.w);
        v8[4] = f2bc(f1.x); v8[5] = f2bc(f1.y); v8[6] = f2bc(f1.z); v8[7] = f2bc(f1.w);
        *(uint4*)&sFeat[r][c8] = *(uint4*)v8;
    }
    if (tid < 128) {   // dists -> raw weight + PE(dist,L=2) cols 32..43; zero 44..63
        int gr = pb * KNBR + tid;
        float x = dists[gr * 3 + 0];
        float y = dists[gr * 3 + 1];
        float z = dists[gr * 3 + 2];
        float d2 = x * x + y * y + z * z;
        sWraw[tid] = (float)mask[gr] / fmaxf(d2, 1e-8f);
        float xs[3] = {x, y, z};
        #pragma unroll
        for (int d = 0; d < 3; d++) {
            #pragma unroll
            for (int l = 0; l < 2; l++) {
                float ang = xs[d] * (float)(1 << l);
                sFeat[tid][32 + d * 4 + l]     = f2bc(__sinf(ang));
                sFeat[tid][32 + d * 4 + 2 + l] = f2bc(__cosf(ang));
            }
        }
        #pragma unroll
        for (int c = 44; c < 64; c++) sFeat[tid][c] = 0;
    }
    __syncthreads();
    if (tid < 128) {
        int lp = tid >> 3;
        float s = 0.f;
        #pragma unroll
        for (int k = 0; k < 8; k++) s += sWraw[lp * 8 + k];
        sWn[tid] = sWraw[tid] / fmaxf(s, 1e-8f);
    }

    f32x4 acc[16];
    #pragma unroll
    for (int i = 0; i < 16; i++) acc[i] = (f32x4){0.f, 0.f, 0.f, 0.f};

    // ---- layer 1: K=64 (44 real) ----
    #pragma unroll
    for (int ki = 0; ki < 2; ki++) {
        bf16x8 a[4];
        #pragma unroll
        for (int mt = 0; mt < 4; mt++)
            a[mt] = *(const bf16x8*)&sFeat[rowB + mt * 16 + n0][ki * 32 + quad * 8];
        const ushort_t* bp = ws + W1S_OFF + ki * 8192 + quad * 2048 + (colB + n0) * 8;
        #pragma unroll
        for (int nt = 0; nt < 4; nt++) {
            bf16x8 b = *(const bf16x8*)(bp + nt * 128);
            #pragma unroll
            for (int mt = 0; mt < 4; mt++)
                acc[mt * 4 + nt] = __builtin_amdgcn_mfma_f32_16x16x32_bf16(a[mt], b, acc[mt * 4 + nt], 0, 0, 0);
        }
    }
    __syncthreads();

    {   // epilogue 1: bias+relu -> sH1 (overwrites sFeat region)
        #pragma unroll
        for (int nt = 0; nt < 4; nt++) {
            int col = colB + nt * 16 + n0;
            float bias = b1[col];
            #pragma unroll
            for (int mt = 0; mt < 4; mt++)
                #pragma unroll
                for (int r = 0; r < 4; r++)
                    sH1[rowB + mt * 16 + quad * 4 + r][col] = f2bc(fmaxf(acc[mt * 4 + nt][r] + bias, 0.f));
        }
    }

    // ---- layer 2 (early): own k-tiles ki = 2wn, 2wn+1, pre-barrier.
    //      Reads only rows rowB..+63 x cols colB..+63 — data THIS wave
    //      just wrote; intra-wave ds ordering (lgkmcnt) makes it safe.
    f32x4 acc2[16];
    #pragma unroll
    for (int i = 0; i < 16; i++) acc2[i] = (f32x4){0.f, 0.f, 0.f, 0.f};
    #pragma unroll
    for (int kio = 0; kio < 2; kio++) {
        int ki = 2 * wn + kio;          // wave-uniform
        bf16x8 a[4];
        #pragma unroll
        for (int mt = 0; mt < 4; mt++)
            a[mt] = *(const bf16x8*)&sH1[rowB + mt * 16 + n0][ki * 32 + quad * 8];
        const ushort_t* bp = ws + W2S_OFF + ki * 8192 + quad * 2048 + (colB + n0) * 8;
        #pragma unroll
        for (int nt = 0; nt < 4; nt++) {
            bf16x8 b = *(const bf16x8*)(bp + nt * 128);
            #pragma unroll
            for (int mt = 0; mt < 4; mt++)
                acc2[mt * 4 + nt] = __builtin_amdgcn_mfma_f32_16x16x32_bf16(a[mt], b, acc2[mt * 4 + nt], 0, 0, 0);
        }
    }
    __syncthreads();

    // ---- layer 2 (rest): remaining 6 k-tiles ----
    #pragma unroll
    for (int ki2 = 0; ki2 < 6; ki2++) {
        int ki = ki2 + ((ki2 >= 2 * wn) ? 2 : 0);   // skip own pair
        bf16x8 a[4];
        #pragma unroll
        for (int mt = 0; mt < 4; mt++)
            a[mt] = *(const bf16x8*)&sH1[rowB + mt * 16 + n0][ki * 32 + quad * 8];
        const ushort_t* bp = ws + W2S_OFF + ki * 8192 + quad * 2048 + (colB + n0) * 8;
        #pragma unroll
        for (int nt = 0; nt < 4; nt++) {
            bf16x8 b = *(const bf16x8*)(bp + nt * 128);
            #pragma unroll
            for (int mt = 0; mt < 4; mt++)
                acc2[mt * 4 + nt] = __builtin_amdgcn_mfma_f32_16x16x32_bf16(a[mt], b, acc2[mt * 4 + nt], 0, 0, 0);
        }
    }
    {   // epilogue 2: relu + neighbor-weighted sum -> global agg (bf16)
        #pragma unroll
        for (int mt = 0; mt < 4; mt++) {
            f32x4 wn4 = *(const f32x4*)&sWn[rowB + mt * 16 + quad * 4];
            #pragma unroll
            for (int nt = 0; nt < 4; nt++) {
                int col = colB + nt * 16 + n0;
                float bias = b2[col];
                float s = fmaxf(acc2[mt * 4 + nt][0] + bias, 0.f) * wn4[0]
                        + fmaxf(acc2[mt * 4 + nt][1] + bias, 0.f) * wn4[1]
                        + fmaxf(acc2[mt * 4 + nt][2] + bias, 0.f) * wn4[2]
                        + fmaxf(acc2[mt * 4 + nt][3] + bias, 0.f) * wn4[3];
                s += __shfl_xor(s, 16);
                if ((quad & 1) == 0) {
                    int pt = pb + 8 * wm + 2 * mt + (quad >> 1);
                    aggg[(size_t)pt * 256 + col] = f2bc(s);
                }
            }
        }
    }
}

// ------------------------------------------------------------------
// kernel B: branch MLPs, 32 points / block, 4 waves. Hidden layers
// N-split; final 256->{1,3} projections done with MFMA against
// pre-swizzled wa2/wc2 (N=16 pad). sAh aliases dead sCin.
// setprio around hidden MFMA loops RETAINED (r13: ~10us gain here —
// 4 independent blocks/CU at skewed phases, m191-favorable regime).
// ------------------------------------------------------------------
__global__ __launch_bounds__(256) void pa_branch(
    const float* __restrict__ vdirs,
    const float* __restrict__ ba1v, const float* __restrict__ ba2v,
    const float* __restrict__ bc1v, const float* __restrict__ bc2v,
    const ushort_t* __restrict__ ws, const ushort_t* __restrict__ aggg,
    float* __restrict__ out)
{
    __shared__ __align__(16) ushort_t reg1[32 * 296];  // sCin; later sAh[32][264]
    __shared__ __align__(16) ushort_t reg2[32 * 264];  // sCh
    ushort_t (*sCin)[296] = (ushort_t(*)[296])reg1;
    ushort_t (*sAh)[264]  = (ushort_t(*)[264])reg1;
    ushort_t (*sCh)[264]  = (ushort_t(*)[264])reg2;

    const int tid  = threadIdx.x;
    const int lane = tid & 63;
    const int wv   = tid >> 6;
    const int n0   = lane & 15;
    const int quad = lane >> 4;
    const int pb   = blockIdx.x * PTS_B;
    const int colB = wv * 64;

    // ---- staging ----
    #pragma unroll
    for (int it = 0; it < 4; it++) {   // agg: 32*256 = 8192 ushorts
        int idx = (tid + it * 256) * 8;
        uint4 v = *(const uint4*)(aggg + (size_t)pb * 256 + idx);
        *(uint4*)&sCin[idx >> 8][idx & 255] = v;
    }
    #pragma unroll
    for (int it = 0; it < 3; it++) {   // PE(viewdirs,L=4): 32*24 = 768
        int t = tid + it * 256;
        int p = t / 24, j = t % 24;
        int d = j >> 3, jj = j & 7, l = jj & 3, isc = jj >> 2;
        float ang = vdirs[(pb + p) * 3 + d] * (float)(1 << l);
        sCin[p][256 + j] = f2bc(isc ? __cosf(ang) : __sinf(ang));
    }
    sCin[tid >> 3][280 + (tid & 7)] = 0;   // K-pad cols
    __syncthreads();

    f32x4 accA[8], accC[8];   // [mt 0..1][nt 0..3]
    #pragma unroll
    for (int i = 0; i < 8; i++) { accA[i] = (f32x4){0.f, 0.f, 0.f, 0.f}; accC[i] = accA[i]; }

    // ---- alpha hidden: K=256 ----
    __builtin_amdgcn_s_setprio(1);
    #pragma unroll
    for (int ki = 0; ki < 8; ki++) {
        bf16x8 a0 = *(const bf16x8*)&sCin[n0][ki * 32 + quad * 8];
        bf16x8 a1 = *(const bf16x8*)&sCin[16 + n0][ki * 32 + quad * 8];
        const ushort_t* bp = ws + WA1S_OFF + ki * 8192 + quad * 2048 + (colB + n0) * 8;
        #pragma unroll
        for (int nt = 0; nt < 4; nt++) {
            bf16x8 b = *(const bf16x8*)(bp + nt * 128);
            accA[nt]     = __builtin_amdgcn_mfma_f32_16x16x32_bf16(a0, b, accA[nt], 0, 0, 0);
            accA[4 + nt] = __builtin_amdgcn_mfma_f32_16x16x32_bf16(a1, b, accA[4 + nt], 0, 0, 0);
        }
    }
    // ---- color hidden: K=288 (280 real) ----
    #pragma unroll
    for (int ki = 0; ki < 9; ki++) {
        bf16x8 a0 = *(const bf16x8*)&sCin[n0][ki * 32 + quad * 8];
        bf16x8 a1 = *(const bf16x8*)&sCin[16 + n0][ki * 32 + quad * 8];
        const ushort_t* bp = ws + WC1S_OFF + ki * 8192 + quad * 2048 + (colB + n0) * 8;
        #pragma unroll
        for (int nt = 0; nt < 4; nt++) {
            bf16x8 b = *(const bf16x8*)(bp + nt * 128);
            accC[nt]     = __builtin_amdgcn_mfma_f32_16x16x32_bf16(a0, b, accC[nt], 0, 0, 0);
            accC[4 + nt] = __builtin_amdgcn_mfma_f32_16x16x32_bf16(a1, b, accC[4 + nt], 0, 0, 0);
        }
    }
    __builtin_amdgcn_s_setprio(0);
    __syncthreads();   // all sCin reads complete before sAh overwrites it

    #pragma unroll
    for (int nt = 0; nt < 4; nt++) {
        int col = colB + nt * 16 + n0;
        float biasA = ba1v[col];
        float biasC = bc1v[col];
        #pragma unroll
        for (int mt = 0; mt < 2; mt++)
            #pragma unroll
            for (int r = 0; r < 4; r++) {
                int row = mt * 16 + quad * 4 + r;
                sAh[row][col] = f2bc(fmaxf(accA[mt * 4 + nt][r] + biasA, 0.f));
                sCh[row][col] = f2bc(fmaxf(accC[mt * 4 + nt][r] + biasC, 0.f));
            }
    }
    __syncthreads();

    // ---- finals via MFMA: wave0/1 alpha m-tiles, wave2/3 color m-tiles ----
    {
        const int isColor = wv >> 1;
        const int baseM   = (wv & 1) * 16;
        const ushort_t* A = isColor ? &sCh[0][0] : &sAh[0][0];
        const ushort_t* B = ws + (isColor ? WC2S_OFF : WA2S_OFF);
        f32x4 acc4 = (f32x4){0.f, 0.f, 0.f, 0.f};
        #pragma unroll
        for (int ki = 0; ki < 8; ki++) {
            bf16x8 a = *(const bf16x8*)(A + (baseM + n0) * 264 + ki * 32 + quad * 8);
            bf16x8 b = *(const bf16x8*)(B + ki * 512 + quad * 128 + n0 * 8);
            acc4 = __builtin_amdgcn_mfma_f32_16x16x32_bf16(a, b, acc4, 0, 0, 0);
        }
        if (!isColor) {
            if (n0 == 0) {
                float ba2s = ba2v[0];
                #pragma unroll
                for (int r = 0; r < 4; r++) {
                    int gp = pb + baseM + quad * 4 + r;
                    float yv = acc4[r] + ba2s - 1.0f;
                    out[(size_t)gp * 4] = (yv > 20.f) ? yv : log1pf(expf(yv));
                }
            }
        } else {
            if (n0 < 3) {
                float bc2s = bc2v[n0];
                #pragma unroll
                for (int r = 0; r < 4; r++) {
                    int gp = pb + baseM + quad * 4 + r;
                    float sig = 1.f / (1.f + expf(-(acc4[r] + bc2s)));
                    out[(size_t)gp * 4 + 1 + n0] = sig * (1.0f + 2e-3f) - 1e-3f;
                }
            }
        }
    }
}

extern "C" void kernel_launch(void* const* d_in, const int* in_sizes, int n_in,
                              void* d_out, int out_size, void* d_ws, size_t ws_size,
                              hipStream_t stream) {
    const float* emb   = (const float*)d_in[0];
    const float* dists = (const float*)d_in[1];
    const float* vdir  = (const float*)d_in[2];
    const int*   mask  = (const int*)d_in[3];
    const float* w1    = (const float*)d_in[4];
    const float* b1    = (const float*)d_in[5];
    const float* w2    = (const float*)d_in[6];
    const float* b2    = (const float*)d_in[7];
    const float* wa1   = (const float*)d_in[8];
    const float* ba1   = (const float*)d_in[9];
    const float* wa2   = (const float*)d_in[10];
    const float* ba2   = (const float*)d_in[11];
    const float* wc1   = (const float*)d_in[12];
    const float* bc1   = (const float*)d_in[13];
    const float* wc2   = (const float*)d_in[14];
    const float* bc2   = (const float*)d_in[15];
    ushort_t* ws  = (ushort_t*)d_ws;
    float*    out = (float*)d_out;

    prep_swizzle<<<dim3((WS_WEIGHT + 255) / 256), dim3(256), 0, stream>>>(
        w1, w2, wa1, wc1, wa2, wc2, ws);
    pa_mlp<<<dim3(NBLK_A), dim3(512), 0, stream>>>(
        emb, dists, mask, b1, b2, ws, ws + AGG_OFF);
    pa_branch<<<dim3(NBLK_B), dim3(256), 0, stream>>>(
        vdir, ba1, ba2, bc1, bc2, ws, ws + AGG_OFF, out);
}